// Round 6
// baseline (163.270 us; speedup 1.0000x reference)
//
#include <hip/hip_runtime.h>
#include <math.h>

#define BB 4
#define CC 128
#define HW 4096
// sqrt(10 * log2(e)) — folds 1/tau AND exp->exp2 into both normalized sides:
// sim' = sim * log2(e), so exp(sim) == exp2(sim').
#define SCF 3.798282565f

typedef short short8 __attribute__((ext_vector_type(8)));
typedef float f32x4 __attribute__((ext_vector_type(4)));

static __device__ inline unsigned short f2bf(float f) {
  // round-to-nearest-even fp32 -> bf16 (inputs are finite)
  unsigned int u = __float_as_uint(f);
  u += 0x7fffu + ((u >> 16) & 1u);
  return (unsigned short)(u >> 16);
}

// K1: per 32-position tile: inv-norms of A and B, fp32 diagonal similarity,
// zero expsum + completion counter, and write bf16 normalized*SCF features
// transposed to [b][pos][c] with XOR-swizzled 16B chunks (position q holds
// data chunk q^(n&7)). B-tile LDS staging stays an identity copy; A/B fragment
// reads apply the XOR in the address (lane-constant), keeping accesses
// conflict-free / 64B-coalesced.
__global__ __launch_bounds__(256) void k_prep(const float* __restrict__ fA,
                                              const float* __restrict__ fB,
                                              unsigned short* __restrict__ fAn,
                                              unsigned short* __restrict__ fBn,
                                              float* __restrict__ diag,
                                              float* __restrict__ expsum,
                                              float* __restrict__ acc) {
  __shared__ float sA[32 * 129];
  __shared__ float sB[32 * 129];
  __shared__ float red[3 * 256];

  const int bid = blockIdx.x;          // 0..511 : b*128 + tile
  const int b   = bid >> 7;
  const int n0  = (bid & 127) * 32;
  const int tid = threadIdx.x;
  const int cR  = tid >> 5;            // 0..7
  const int n   = tid & 31;            // 0..31

  if (bid == 0 && tid == 0) { acc[0] = 0.f; acc[1] = 0.f; ((unsigned*)acc)[2] = 0u; }

  const float* pa = fA + (size_t)b * CC * HW + n0 + n;
  const float* pb = fB + (size_t)b * CC * HW + n0 + n;

  float ssa = 0.f, ssb = 0.f, dot = 0.f;
  #pragma unroll
  for (int it = 0; it < 16; ++it) {
    int c = it * 8 + cR;
    float va = pa[(size_t)c * HW];
    float vb = pb[(size_t)c * HW];
    sA[n * 129 + c] = va;
    sB[n * 129 + c] = vb;
    ssa = fmaf(va, va, ssa);
    ssb = fmaf(vb, vb, ssb);
    dot = fmaf(va, vb, dot);
  }
  red[tid] = ssa; red[256 + tid] = ssb; red[512 + tid] = dot;
  __syncthreads();

  if (tid < 32) {
    float sa = 0.f, sb = 0.f, dt = 0.f;
    #pragma unroll
    for (int k = 0; k < 8; ++k) {
      sa += red[k * 32 + tid];
      sb += red[256 + k * 32 + tid];
      dt += red[512 + k * 32 + tid];
    }
    float ia = 1.f / fmaxf(sqrtf(sa), 1e-12f);
    float ib = 1.f / fmaxf(sqrtf(sb), 1e-12f);
    int gidx = b * HW + n0 + tid;
    diag[gidx]   = dt * ia * ib * 10.f;   // true sim scale (1/tau)
    expsum[gidx] = 0.f;
    red[tid]      = ia * SCF;   // sole reader/writer of these slots
    red[32 + tid] = ib * SCF;
  }
  __syncthreads();

  #pragma unroll
  for (int r = 0; r < 2; ++r) {
    int L  = r * 256 + tid;
    int nn = L >> 4;                  // 0..31
    int q  = L & 15;                  // store position within row
    int c0 = (q ^ (nn & 7)) * 8;      // data chunk (swizzle)
    size_t base = ((size_t)b * HW + n0 + nn) * 128 + q * 8;
    {
      float sc = red[nn];
      const float* s = &sA[nn * 129 + c0];
      uint4 v;
      v.x = f2bf(s[0]*sc) | ((unsigned)f2bf(s[1]*sc) << 16);
      v.y = f2bf(s[2]*sc) | ((unsigned)f2bf(s[3]*sc) << 16);
      v.z = f2bf(s[4]*sc) | ((unsigned)f2bf(s[5]*sc) << 16);
      v.w = f2bf(s[6]*sc) | ((unsigned)f2bf(s[7]*sc) << 16);
      *(uint4*)(fAn + base) = v;
    }
    {
      float sc = red[32 + nn];
      const float* s = &sB[nn * 129 + c0];
      uint4 v;
      v.x = f2bf(s[0]*sc) | ((unsigned)f2bf(s[1]*sc) << 16);
      v.y = f2bf(s[2]*sc) | ((unsigned)f2bf(s[3]*sc) << 16);
      v.z = f2bf(s[4]*sc) | ((unsigned)f2bf(s[5]*sc) << 16);
      v.w = f2bf(s[6]*sc) | ((unsigned)f2bf(s[7]*sc) << 16);
      *(uint4*)(fBn + base) = v;
    }
  }
}

// K2: barrier-free K-loop. B-tile (32 KB) staged to LDS once (single barrier),
// B-fragments extracted to registers. Each wave sweeps its 256 A-rows in
// 16-row chunks loaded DIRECTLY global->VGPR (4x dwordx4, depth-2 pipeline,
// per-register vmcnt waits) — no LDS ping-pong, no per-iter __syncthreads.
// LDS = 32 KB + eps -> up to 4 blocks/CU by LDS; ~140 VGPR -> 3 waves/SIMD.
// Fused exp2 column-sum epilogue + last-block loss finish.
__global__ __launch_bounds__(256, 3) void k_main(const unsigned short* __restrict__ fAn,
                                                 const unsigned short* __restrict__ fBn,
                                                 float* __restrict__ expsum,
                                                 const float* __restrict__ diag,
                                                 const float* __restrict__ mask,
                                                 float* __restrict__ acc,
                                                 float* __restrict__ out) {
  __shared__ unsigned short sB[16384];   // 32 KB B tile (128 cols x 128 ch)
  __shared__ float redS[16];
  __shared__ unsigned flagS;

  const int bid = blockIdx.x;                 // 0..1023
  const int x   = bid & 7;                    // XCD
  const int t   = bid >> 3;                   // 0..127
  const int b   = x & 3;
  const int nq  = ((x >> 2) << 2) | (t & 3);  // 0..7 (n-eighth)
  const int mt  = t >> 2;                     // 0..31
  const int m0  = mt * 128;
  const int n0  = nq * 512;
  const int tid = threadIdx.x;

  const int wv   = tid >> 6;
  const int lane = tid & 63;
  const int ml   = lane & 15;
  const int g    = lane >> 4;
  const int wm   = (wv & 1) * 64;    // wave m-offset within B tile
  const int wn   = (wv >> 1) * 256;  // wave n-offset within the 512-row eighth

  // stage B tile once
  {
    const unsigned short* gB = fBn + ((size_t)b * HW + m0) * 128;
    #pragma unroll
    for (int r = 0; r < 8; ++r) {
      int L = r * 256 + tid;
      __builtin_amdgcn_global_load_lds(
          (const __attribute__((address_space(1))) unsigned int*)(gB + (size_t)L * 8),
          (__attribute__((address_space(3))) unsigned int*)(sB + L * 8), 16, 0, 0);
    }
  }
  __syncthreads();   // the only barrier before the epilogue

  // B fragments -> registers (64 VGPR), applying the XOR swizzle in-address
  short8 bf[4][4];
  #pragma unroll
  for (int kc = 0; kc < 4; ++kc) {
    #pragma unroll
    for (int j = 0; j < 4; ++j) {
      int nb = wm + j * 16 + ml;
      bf[kc][j] = *(const short8*)(sB + nb * 128 + (((kc * 4 + g) ^ (nb & 7)) * 8));
    }
  }

  // per-lane A addressing: row = n0+wn+ml advances 16 rows (2048 shorts)/chunk
  const unsigned short* pA = fAn + ((size_t)b * HW + n0 + wn + ml) * 128;
  int xoff[4];
  #pragma unroll
  for (int kc = 0; kc < 4; ++kc) xoff[kc] = ((kc * 4 + g) ^ (ml & 7)) * 8;

  float colAcc[4] = {0.f, 0.f, 0.f, 0.f};
  short8 afA[4], afB[4];

  #pragma unroll
  for (int kc = 0; kc < 4; ++kc)
    afA[kc] = *(const short8*)(pA + xoff[kc]);           // chunk 0

  #pragma unroll
  for (int c = 0; c < 16; c += 2) {
    #pragma unroll
    for (int kc = 0; kc < 4; ++kc)                        // prefetch chunk c+1
      afB[kc] = *(const short8*)(pA + (size_t)(c + 1) * 2048 + xoff[kc]);
    {
      f32x4 a4[4] = {};
      #pragma unroll
      for (int kc = 0; kc < 4; ++kc)
        #pragma unroll
        for (int j = 0; j < 4; ++j)
          a4[j] = __builtin_amdgcn_mfma_f32_16x16x32_bf16(afA[kc], bf[kc][j], a4[j], 0, 0, 0);
      #pragma unroll
      for (int j = 0; j < 4; ++j)
        #pragma unroll
        for (int r = 0; r < 4; ++r)
          colAcc[j] += exp2f(a4[j][r]);
    }
    if (c + 2 < 16) {
      #pragma unroll
      for (int kc = 0; kc < 4; ++kc)                      // prefetch chunk c+2
        afA[kc] = *(const short8*)(pA + (size_t)(c + 2) * 2048 + xoff[kc]);
    }
    {
      f32x4 a4[4] = {};
      #pragma unroll
      for (int kc = 0; kc < 4; ++kc)
        #pragma unroll
        for (int j = 0; j < 4; ++j)
          a4[j] = __builtin_amdgcn_mfma_f32_16x16x32_bf16(afB[kc], bf[kc][j], a4[j], 0, 0, 0);
      #pragma unroll
      for (int j = 0; j < 4; ++j)
        #pragma unroll
        for (int r = 0; r < 4; ++r)
          colAcc[j] += exp2f(a4[j][r]);
    }
  }

  // per-column reduce across the 4 row-groups, one atomic per column per wave
  #pragma unroll
  for (int j = 0; j < 4; ++j) {
    float e = colAcc[j];
    e += __shfl_xor(e, 16, 64);
    e += __shfl_xor(e, 32, 64);
    if (lane < 16)
      atomicAdd(&expsum[(size_t)b * HW + m0 + wm + j * 16 + lane], e);
  }

  // last-block loss finish
  __syncthreads();                 // all waves' atomics issued
  if (tid == 0) {
    __threadfence();
    flagS = (atomicAdd((unsigned*)(acc + 2), 1u) == 1023u) ? 1u : 0u;
  }
  __syncthreads();
  if (flagS) {
    float num = 0.f, den = 0.f;
    #pragma unroll 4
    for (int i = tid; i < BB * HW; i += 256) {
      float es = __hip_atomic_load(expsum + i, __ATOMIC_RELAXED, __HIP_MEMORY_SCOPE_AGENT);
      float mv = mask[i];
      num = fmaf(mv, __logf(es) - diag[i], num);   // ln(sum exp(sim)) - sim_kk
      den += mv;
    }
    #pragma unroll
    for (int off = 32; off; off >>= 1) {
      num += __shfl_down(num, off, 64);
      den += __shfl_down(den, off, 64);
    }
    if (lane == 0) { redS[wv] = num; redS[8 + wv] = den; }
    __syncthreads();
    if (tid == 0) {
      float n = redS[0] + redS[1] + redS[2] + redS[3];
      float d = redS[8] + redS[9] + redS[10] + redS[11];
      out[0] = n / (d + 1e-6f);
    }
  }
}

extern "C" void kernel_launch(void* const* d_in, const int* in_sizes, int n_in,
                              void* d_out, int out_size, void* d_ws, size_t ws_size,
                              hipStream_t stream) {
  const float* feat_A = (const float*)d_in[0];
  const float* feat_B = (const float*)d_in[1];
  // d_in[2] = H_mat : unused by the reference computation
  const float* vmask  = (const float*)d_in[3];

  unsigned short* fAn = (unsigned short*)d_ws;            // 4 MB bf16 [b][n][c] swizzled
  unsigned short* fBn = fAn + (size_t)BB * HW * CC;       // 4 MB
  float* diag   = (float*)(fBn + (size_t)BB * HW * CC);   // 64 KB
  float* expsum = diag + BB * HW;                         // 64 KB
  float* acc    = expsum + BB * HW;                       // num, den, counter
  float* out    = (float*)d_out;

  k_prep<<<512,  256, 0, stream>>>(feat_A, feat_B, fAn, fBn, diag, expsum, acc);
  k_main<<<1024, 256, 0, stream>>>(fAn, fBn, expsum, diag, vmask, acc, out);
}

// Round 7
// 160.412 us; speedup vs baseline: 1.0178x; 1.0178x over previous
//
#include <hip/hip_runtime.h>
#include <math.h>

#define BB 4
#define CC 128
#define HW 4096
// sqrt(10 * log2(e)) — folds 1/tau AND exp->exp2 into both normalized sides:
// sim' = sim * log2(e), so exp(sim) == exp2(sim').
#define SCF 3.798282565f

typedef short short8 __attribute__((ext_vector_type(8)));
typedef float f32x4 __attribute__((ext_vector_type(4)));

static __device__ inline unsigned short f2bf(float f) {
  // round-to-nearest-even fp32 -> bf16 (inputs are finite)
  unsigned int u = __float_as_uint(f);
  u += 0x7fffu + ((u >> 16) & 1u);
  return (unsigned short)(u >> 16);
}

// Fragment-major layout: for batch b, 16-position chunk t, k-slice kc, the
// 64 lanes' 16B fragments are stored contiguously:
//   addr(b,t,kc,lane) = (((b*256 + t)*4 + kc)*64 + lane) * 8 shorts
// where lane = g*16 + ml holds position t*16+ml, channels (kc*4+g)*8..+8.
// Every MFMA fragment load (A and B alike) becomes ONE contiguous 1KB
// wave-load — perfectly coalesced, no LDS staging, no swizzle.

// K1: per 32-position tile: inv-norms of A and B, fp32 diagonal similarity,
// zero expsum + completion counter, write bf16 normalized*SCF features in
// fragment-major order (coalesced 4KB stores per round).
__global__ __launch_bounds__(256) void k_prep(const float* __restrict__ fA,
                                              const float* __restrict__ fB,
                                              unsigned short* __restrict__ fAn,
                                              unsigned short* __restrict__ fBn,
                                              float* __restrict__ diag,
                                              float* __restrict__ expsum,
                                              float* __restrict__ acc) {
  __shared__ float sA[32 * 129];
  __shared__ float sB[32 * 129];
  __shared__ float red[3 * 256];

  const int bid = blockIdx.x;          // 0..511 : b*128 + tile
  const int b   = bid >> 7;
  const int n0  = (bid & 127) * 32;
  const int tid = threadIdx.x;
  const int cR  = tid >> 5;            // 0..7
  const int n   = tid & 31;            // 0..31

  if (bid == 0 && tid == 0) { acc[0] = 0.f; acc[1] = 0.f; ((unsigned*)acc)[2] = 0u; }

  const float* pa = fA + (size_t)b * CC * HW + n0 + n;
  const float* pb = fB + (size_t)b * CC * HW + n0 + n;

  float ssa = 0.f, ssb = 0.f, dot = 0.f;
  #pragma unroll
  for (int it = 0; it < 16; ++it) {
    int c = it * 8 + cR;
    float va = pa[(size_t)c * HW];
    float vb = pb[(size_t)c * HW];
    sA[n * 129 + c] = va;
    sB[n * 129 + c] = vb;
    ssa = fmaf(va, va, ssa);
    ssb = fmaf(vb, vb, ssb);
    dot = fmaf(va, vb, dot);
  }
  red[tid] = ssa; red[256 + tid] = ssb; red[512 + tid] = dot;
  __syncthreads();

  if (tid < 32) {
    float sa = 0.f, sb = 0.f, dt = 0.f;
    #pragma unroll
    for (int k = 0; k < 8; ++k) {
      sa += red[k * 32 + tid];
      sb += red[256 + k * 32 + tid];
      dt += red[512 + k * 32 + tid];
    }
    float ia = 1.f / fmaxf(sqrtf(sa), 1e-12f);
    float ib = 1.f / fmaxf(sqrtf(sb), 1e-12f);
    int gidx = b * HW + n0 + tid;
    diag[gidx]   = dt * ia * ib * 10.f;   // true sim scale (1/tau)
    expsum[gidx] = 0.f;
    red[tid]      = ia * SCF;   // sole reader/writer of these slots
    red[32 + tid] = ib * SCF;
  }
  __syncthreads();

  // write phase: fragment-major. Per round r, the 256 threads emit one
  // contiguous 4KB t-chunk per matrix: tid = kc*64 + g*16 + ml.
  const int ml = tid & 15;
  const int g  = (tid >> 4) & 3;
  const int kc = tid >> 6;
  #pragma unroll
  for (int r = 0; r < 2; ++r) {
    int nn = r * 16 + ml;             // row within the 32-row tile
    int c0 = (kc * 4 + g) * 8;        // channel base
    size_t base = ((((size_t)b * 256 + (n0 >> 4) + r) * 4 + kc) * 64 + (g * 16 + ml)) * 8;
    {
      float sc = red[nn];
      const float* s = &sA[nn * 129 + c0];
      uint4 v;
      v.x = f2bf(s[0]*sc) | ((unsigned)f2bf(s[1]*sc) << 16);
      v.y = f2bf(s[2]*sc) | ((unsigned)f2bf(s[3]*sc) << 16);
      v.z = f2bf(s[4]*sc) | ((unsigned)f2bf(s[5]*sc) << 16);
      v.w = f2bf(s[6]*sc) | ((unsigned)f2bf(s[7]*sc) << 16);
      *(uint4*)(fAn + base) = v;
    }
    {
      float sc = red[32 + nn];
      const float* s = &sB[nn * 129 + c0];
      uint4 v;
      v.x = f2bf(s[0]*sc) | ((unsigned)f2bf(s[1]*sc) << 16);
      v.y = f2bf(s[2]*sc) | ((unsigned)f2bf(s[3]*sc) << 16);
      v.z = f2bf(s[4]*sc) | ((unsigned)f2bf(s[5]*sc) << 16);
      v.w = f2bf(s[6]*sc) | ((unsigned)f2bf(s[7]*sc) << 16);
      *(uint4*)(fBn + base) = v;
    }
  }
}

// K2: LDS-free, barrier-free K-loop. Each wave: load its 16 B-fragments once
// (64 VGPR, coalesced), then sweep 16 A-chunks (16 rows each) with depth-2
// register pipelining — every fragment load is a contiguous 1KB wave-load.
// Fused exp2 column-sum epilogue (one atomic per column per wave) +
// last-block loss finish. No LDS => occupancy bounded only by VGPRs (~140
// -> 3 waves/SIMD).
__global__ __launch_bounds__(256, 3) void k_main(const unsigned short* __restrict__ fAn,
                                                 const unsigned short* __restrict__ fBn,
                                                 float* __restrict__ expsum,
                                                 const float* __restrict__ diag,
                                                 const float* __restrict__ mask,
                                                 float* __restrict__ acc,
                                                 float* __restrict__ out) {
  __shared__ float redS[16];
  __shared__ unsigned flagS;

  const int bid = blockIdx.x;                 // 0..1023
  const int x   = bid & 7;                    // XCD (heuristic: bid%8)
  const int t   = bid >> 3;                   // 0..127
  const int b   = x & 3;
  const int nq  = ((x >> 2) << 2) | (t & 3);  // 0..7 (512-row n-slice)
  const int mt  = t >> 2;                     // 0..31 (128-col m-tile)
  const int tid = threadIdx.x;

  const int wv   = tid >> 6;
  const int lane = tid & 63;
  const int wm   = (wv & 1) * 64;    // wave m-offset within the 128-col tile
  const int wn   = (wv >> 1) * 256;  // wave n-offset within the 512-row slice

  // B fragments -> registers: cols mt*128+wm .. +63 = t-chunks tB0..tB0+3
  const int tB0 = (mt * 128 + wm) >> 4;
  const unsigned short* gB = fBn + (((size_t)b * 256 + tB0) * 4) * 512;
  short8 bf[4][4];
  #pragma unroll
  for (int j = 0; j < 4; ++j)
    #pragma unroll
    for (int kc = 0; kc < 4; ++kc)
      bf[kc][j] = *(const short8*)(gB + ((size_t)j * 4 + kc) * 512 + lane * 8);

  // A stream: t-chunks tA0 .. tA0+15  (chunk stride 2048 shorts = 4KB)
  const int tA0 = (nq * 512 + wn) >> 4;
  const unsigned short* pA = fAn + (((size_t)b * 256 + tA0) * 4) * 512;

  float colAcc[4] = {0.f, 0.f, 0.f, 0.f};
  short8 afA[4], afB[4];

  #pragma unroll
  for (int kc = 0; kc < 4; ++kc)
    afA[kc] = *(const short8*)(pA + (size_t)kc * 512 + lane * 8);   // chunk 0

  #pragma unroll
  for (int c = 0; c < 16; c += 2) {
    #pragma unroll
    for (int kc = 0; kc < 4; ++kc)                                   // chunk c+1
      afB[kc] = *(const short8*)(pA + (size_t)(c + 1) * 2048 + kc * 512 + lane * 8);
    {
      f32x4 a4[4] = {};
      #pragma unroll
      for (int kc = 0; kc < 4; ++kc)
        #pragma unroll
        for (int j = 0; j < 4; ++j)
          a4[j] = __builtin_amdgcn_mfma_f32_16x16x32_bf16(afA[kc], bf[kc][j], a4[j], 0, 0, 0);
      #pragma unroll
      for (int j = 0; j < 4; ++j)
        #pragma unroll
        for (int r = 0; r < 4; ++r)
          colAcc[j] += exp2f(a4[j][r]);
    }
    if (c + 2 < 16) {
      #pragma unroll
      for (int kc = 0; kc < 4; ++kc)                                 // chunk c+2
        afA[kc] = *(const short8*)(pA + (size_t)(c + 2) * 2048 + kc * 512 + lane * 8);
    }
    {
      f32x4 a4[4] = {};
      #pragma unroll
      for (int kc = 0; kc < 4; ++kc)
        #pragma unroll
        for (int j = 0; j < 4; ++j)
          a4[j] = __builtin_amdgcn_mfma_f32_16x16x32_bf16(afB[kc], bf[kc][j], a4[j], 0, 0, 0);
      #pragma unroll
      for (int j = 0; j < 4; ++j)
        #pragma unroll
        for (int r = 0; r < 4; ++r)
          colAcc[j] += exp2f(a4[j][r]);
    }
  }

  // per-column reduce across the 4 row-groups, one atomic per column per wave.
  // C layout: col = lane&15 within group j, row = (lane>>4)*4 + reg.
  const int ml = lane & 15;
  #pragma unroll
  for (int j = 0; j < 4; ++j) {
    float e = colAcc[j];
    e += __shfl_xor(e, 16, 64);
    e += __shfl_xor(e, 32, 64);
    if (lane < 16)
      atomicAdd(&expsum[(size_t)b * HW + mt * 128 + wm + j * 16 + ml], e);
  }

  // last-block loss finish
  __syncthreads();                 // all waves' atomics issued
  if (tid == 0) {
    __threadfence();
    flagS = (atomicAdd((unsigned*)(acc + 2), 1u) == 1023u) ? 1u : 0u;
  }
  __syncthreads();
  if (flagS) {
    float num = 0.f, den = 0.f;
    #pragma unroll 4
    for (int i = tid; i < BB * HW; i += 256) {
      float es = __hip_atomic_load(expsum + i, __ATOMIC_RELAXED, __HIP_MEMORY_SCOPE_AGENT);
      float mv = mask[i];
      num = fmaf(mv, __logf(es) - diag[i], num);   // ln(sum exp(sim)) - sim_kk
      den += mv;
    }
    #pragma unroll
    for (int off = 32; off; off >>= 1) {
      num += __shfl_down(num, off, 64);
      den += __shfl_down(den, off, 64);
    }
    if (lane == 0) { redS[wv] = num; redS[8 + wv] = den; }
    __syncthreads();
    if (tid == 0) {
      float n = redS[0] + redS[1] + redS[2] + redS[3];
      float d = redS[8] + redS[9] + redS[10] + redS[11];
      out[0] = n / (d + 1e-6f);
    }
  }
}

extern "C" void kernel_launch(void* const* d_in, const int* in_sizes, int n_in,
                              void* d_out, int out_size, void* d_ws, size_t ws_size,
                              hipStream_t stream) {
  const float* feat_A = (const float*)d_in[0];
  const float* feat_B = (const float*)d_in[1];
  // d_in[2] = H_mat : unused by the reference computation
  const float* vmask  = (const float*)d_in[3];

  unsigned short* fAn = (unsigned short*)d_ws;            // 4 MB bf16 fragment-major
  unsigned short* fBn = fAn + (size_t)BB * HW * CC;       // 4 MB
  float* diag   = (float*)(fBn + (size_t)BB * HW * CC);   // 64 KB
  float* expsum = diag + BB * HW;                         // 64 KB
  float* acc    = expsum + BB * HW;                       // num, den, counter
  float* out    = (float*)d_out;

  k_prep<<<512,  256, 0, stream>>>(feat_A, feat_B, fAn, fBn, diag, expsum, acc);
  k_main<<<1024, 256, 0, stream>>>(fAn, fBn, expsum, diag, vmask, acc, out);
}